// Round 2
// baseline (1687.025 us; speedup 1.0000x reference)
//
#include <hip/hip_runtime.h>
#include <hip/hip_cooperative_groups.h>
#include <cstddef>

namespace cg = cooperative_groups;

constexpr int H  = 512;   // hidden
constexpr int F  = 21;    // features
constexpr int T  = 28;    // output steps
constexpr int NB = 128;   // blocks
constexpr int NT = 256;   // threads/block (4 waves) -> 512 waves total
constexpr int NW = NT / 64;

// All inter-block state in device globals: NO d_ws dependence (ws_size unknown).
// Every slot is written before it is read on every call (no cross-call state).
__device__ float g_enc[H];          // encoder output
__device__ float g_h[2 * 3 * H];    // ping-pong h state [buf][layer][H]
__device__ float g_c[3 * H];        // c state (owner-wave access only)
__device__ float g_base0[4 * H];    // dec layer0 precomputed: Wih0[:,F:]@enc + bih + bhh

struct P {
  const float *x, *py, *eW0, *eW1, *eW2, *ebih, *ebhh;
  const float *dW0, *dW1, *dW2, *dWhh, *dbih, *dbhh, *outW, *outb;
  float* out;
};

__device__ __forceinline__ float sigm(float v)  { return 1.0f / (1.0f + __expf(-v)); }
__device__ __forceinline__ float tanh_f(float v){ return 1.0f - 2.0f / (__expf(2.0f * v) + 1.0f); }

__device__ __forceinline__ float4 wredsum4(float4 v) {
#pragma unroll
  for (int off = 32; off > 0; off >>= 1) {
    v.x += __shfl_xor(v.x, off, 64);
    v.y += __shfl_xor(v.y, off, 64);
    v.z += __shfl_xor(v.z, off, 64);
    v.w += __shfl_xor(v.w, off, 64);
  }
  return v;
}

__device__ __forceinline__ float wredsum1(float v) {
#pragma unroll
  for (int off = 32; off > 0; off >>= 1) v += __shfl_xor(v, off, 64);
  return v;
}

__device__ __forceinline__ void ld8(const float* __restrict__ p, int lane, float4& a, float4& b) {
  a = *(const float4*)(p + lane * 8);
  b = *(const float4*)(p + lane * 8 + 4);
}

// accumulate 4 gate partial dots (length-512 segment), W row-major ld=512
__device__ __forceinline__ void dot4(const float* __restrict__ W, int r, int lane,
                                     float4 x0, float4 x1, float* s) {
#pragma unroll
  for (int g = 0; g < 4; ++g) {
    const float* p = W + (size_t)(g * H + r) * H + lane * 8;
    float4 a = *(const float4*)(p);
    float4 b = *(const float4*)(p + 4);
    s[g] += a.x * x0.x + a.y * x0.y + a.z * x0.z + a.w * x0.w
          + b.x * x1.x + b.y * x1.y + b.z * x1.z + b.w * x1.w;
  }
}

// one row of y = out_W[j,:] . [h2 ; enc], reduced across the wave
__device__ __forceinline__ float ydot(const float* __restrict__ outW,
                                      const float* __restrict__ h2p,
                                      const float* __restrict__ enc,
                                      int j, int lane) {
  const float4* wr = (const float4*)(outW + (size_t)j * (2 * H) + lane * 16);
  const float*  upf = (lane < 32) ? (h2p + lane * 16) : (enc + lane * 16 - H);
  const float4* up  = (const float4*)upf;
  float s = 0.f;
#pragma unroll
  for (int k = 0; k < 4; ++k) {
    float4 a = wr[k];
    float4 u = up[k];
    s += a.x * u.x + a.y * u.y + a.z * u.z + a.w * u.w;
  }
  return wredsum1(s);
}

// ---------------- phase bodies (shared by coop and multi-launch paths) ----------------

// Encoder layer 0: h=c=0 so Whh term vanishes and f-gate is dead.
__device__ __forceinline__ void d_enc0(const P& p, int r, int lane) {
  float s0 = 0.f, s1 = 0.f, s2 = 0.f, s3 = 0.f;
  if (lane < F) {
    const float xv = p.x[lane];
    s0 = p.eW0[(size_t)(0 * H + r) * F + lane] * xv;
    s1 = p.eW0[(size_t)(1 * H + r) * F + lane] * xv;
    s2 = p.eW0[(size_t)(2 * H + r) * F + lane] * xv;
    s3 = p.eW0[(size_t)(3 * H + r) * F + lane] * xv;
  }
  float4 v = wredsum4(make_float4(s0, s1, s2, s3));
  if (lane == 0) {
    const float* bi = p.ebih + r;
    const float* bh = p.ebhh + r;
    float cn = sigm(v.x + bi[0] + bh[0]) * tanh_f(v.z + bi[2 * H] + bh[2 * H]);
    g_c[r] = cn;
    g_h[3 * H + r] = sigm(v.w + bi[3 * H] + bh[3 * H]) * tanh_f(cn);  // buf1, layer0
  }
}

// Encoder layer l (1 or 2); still from h=c=0 so only Wih term + biases.
__device__ __forceinline__ void d_encL(const P& p, const float* W, int l, int r, int lane) {
  const float* hp = g_h + 3 * H + (l - 1) * H;
  float4 x0, x1; ld8(hp, lane, x0, x1);
  float s[4] = {0.f, 0.f, 0.f, 0.f};
  dot4(W, r, lane, x0, x1, s);
  float4 v = wredsum4(make_float4(s[0], s[1], s[2], s[3]));
  if (lane == 0) {
    const float* bi = p.ebih + l * 4 * H + r;
    const float* bh = p.ebhh + l * 4 * H + r;
    float cn = sigm(v.x + bi[0] + bh[0]) * tanh_f(v.z + bi[2 * H] + bh[2 * H]);
    g_c[l * H + r] = cn;
    float hn = sigm(v.w + bi[3 * H] + bh[3 * H]) * tanh_f(cn);
    g_h[3 * H + l * H + r] = hn;
    if (l == 2) g_enc[r] = hn;
  }
}

// base0 = dec_Wih0[:, F:] @ enc_out + dbih[0] + dbhh[0]  (constant over t)
__device__ __forceinline__ void d_base0(const P& p, int r, int lane) {
#pragma unroll
  for (int g = 0; g < 4; ++g) {
    const float* wrow = p.dW0 + (size_t)(g * H + r) * (H + F) + F;
    float s = 0.f;
    for (int j = lane; j < H; j += 64) s += wrow[j] * g_enc[j];
    s = wredsum1(s);
    if (lane == 0) g_base0[g * H + r] = s + p.dbih[g * H + r] + p.dbhh[g * H + r];
  }
}

// Decoder step t, stage 0: y(t-1) (block-redundant) + cell 0.
__device__ __forceinline__ void d_dec_s0(const P& p, int t, int r, int lane, int w,
                                         bool is_b0, float* ly) {
  const int pb = t & 1, ob = pb ^ 1;
  float*       hw = g_h + pb * 3 * H;
  const float* hr = g_h + ob * 3 * H;

  if (t == 0) {
    if (threadIdx.x < F) ly[threadIdx.x] = p.py[threadIdx.x];
  } else {
    const float* h2p = hr + 2 * H;
    for (int j = w; j < F; j += NW) {
      float s = ydot(p.outW, h2p, g_enc, j, lane);
      if (lane == 0) ly[j] = s + p.outb[j];
    }
  }
  __syncthreads();
  if (t > 0 && is_b0 && threadIdx.x < F) p.out[(t - 1) * F + threadIdx.x] = ly[threadIdx.x];

  float4 h0a, h0b; ld8(hr, lane, h0a, h0b);     // h0(t-1)
  float s[4] = {0.f, 0.f, 0.f, 0.f};
  dot4(p.dWhh, r, lane, h0a, h0b, s);           // Whh layer 0
  if (lane < F) {
    const float yv = ly[lane];
#pragma unroll
    for (int g = 0; g < 4; ++g) s[g] += p.dW0[(size_t)(g * H + r) * (H + F) + lane] * yv;
  }
  float4 v = wredsum4(make_float4(s[0], s[1], s[2], s[3]));
  if (lane == 0) {
    float cn = sigm(v.y + g_base0[H + r]) * g_c[r]
             + sigm(v.x + g_base0[r]) * tanh_f(v.z + g_base0[2 * H + r]);
    g_c[r] = cn;
    hw[r] = sigm(v.w + g_base0[3 * H + r]) * tanh_f(cn);
  }
}

// Decoder step t, stage l (1 or 2): cell l.
__device__ __forceinline__ void d_dec_sL(const P& p, const float* Wih, int t, int l,
                                         int r, int lane) {
  const int pb = t & 1, ob = pb ^ 1;
  float*       hw = g_h + pb * 3 * H;
  const float* hr = g_h + ob * 3 * H;
  const float* xp = hw + (l - 1) * H;  // h_{l-1}(t)
  const float* hp = hr + l * H;        // h_l(t-1)
  float4 x0, x1, h0, h1;
  ld8(xp, lane, x0, x1);
  ld8(hp, lane, h0, h1);
  float s[4] = {0.f, 0.f, 0.f, 0.f};
  dot4(Wih, r, lane, x0, x1, s);
  dot4(p.dWhh + (size_t)l * 4 * H * H, r, lane, h0, h1, s);
  float4 v = wredsum4(make_float4(s[0], s[1], s[2], s[3]));
  if (lane == 0) {
    const float* bi = p.dbih + l * 4 * H + r;
    const float* bh = p.dbhh + l * 4 * H + r;
    float pi = v.x + bi[0] + bh[0];
    float pf = v.y + bi[H] + bh[H];
    float pg = v.z + bi[2 * H] + bh[2 * H];
    float po = v.w + bi[3 * H] + bh[3 * H];
    float cn = sigm(pf) * g_c[l * H + r] + sigm(pi) * tanh_f(pg);
    g_c[l * H + r] = cn;
    hw[l * H + r] = sigm(po) * tanh_f(cn);
  }
}

__device__ __forceinline__ void d_final(const P& p, int w, int lane) {
  const float* h2p = g_h + ((T - 1) & 1) * 3 * H + 2 * H;
  for (int j = w; j < F; j += NW) {
    float s = ydot(p.outW, h2p, g_enc, j, lane);
    if (lane == 0) p.out[(T - 1) * F + j] = s + p.outb[j];
  }
}

// ---------------- cooperative single-kernel path ----------------

__global__ __launch_bounds__(NT, 1)
void k_coop(P p) {
  cg::grid_group grid = cg::this_grid();
  const int lane = threadIdx.x & 63;
  const int w    = threadIdx.x >> 6;
  const int r    = blockIdx.x * NW + w;
  __shared__ float ly[32];

  d_enc0(p, r, lane);                 grid.sync();
  d_encL(p, p.eW1, 1, r, lane);       grid.sync();
  d_encL(p, p.eW2, 2, r, lane);       grid.sync();
  d_base0(p, r, lane);                grid.sync();

  for (int t = 0; t < T; ++t) {
    d_dec_s0(p, t, r, lane, w, blockIdx.x == 0, ly); grid.sync();
    d_dec_sL(p, p.dW1, t, 1, r, lane);               grid.sync();
    d_dec_sL(p, p.dW2, t, 2, r, lane);               grid.sync();
  }
  if (blockIdx.x == 0) d_final(p, w, lane);
}

// ---------------- multi-launch fallback path ----------------

__global__ __launch_bounds__(NT) void k_enc0(P p) {
  d_enc0(p, blockIdx.x * NW + (threadIdx.x >> 6), threadIdx.x & 63);
}
__global__ __launch_bounds__(NT) void k_encL(P p, int l) {
  d_encL(p, l == 1 ? p.eW1 : p.eW2, l, blockIdx.x * NW + (threadIdx.x >> 6), threadIdx.x & 63);
}
__global__ __launch_bounds__(NT) void k_base0(P p) {
  d_base0(p, blockIdx.x * NW + (threadIdx.x >> 6), threadIdx.x & 63);
}
__global__ __launch_bounds__(NT) void k_dec_s0(P p, int t) {
  __shared__ float ly[32];
  d_dec_s0(p, t, blockIdx.x * NW + (threadIdx.x >> 6), threadIdx.x & 63,
           threadIdx.x >> 6, blockIdx.x == 0, ly);
}
__global__ __launch_bounds__(NT) void k_dec_sL(P p, int t, int l) {
  d_dec_sL(p, l == 1 ? p.dW1 : p.dW2, t, l,
           blockIdx.x * NW + (threadIdx.x >> 6), threadIdx.x & 63);
}
__global__ __launch_bounds__(NT) void k_final(P p) {
  d_final(p, threadIdx.x >> 6, threadIdx.x & 63);
}

extern "C" void kernel_launch(void* const* d_in, const int* in_sizes, int n_in,
                              void* d_out, int out_size, void* d_ws, size_t ws_size,
                              hipStream_t stream) {
  P p;
  p.x    = (const float*)d_in[0];
  p.py   = (const float*)d_in[1];
  p.eW0  = (const float*)d_in[2];
  p.eW1  = (const float*)d_in[3];
  p.eW2  = (const float*)d_in[4];
  // d_in[5] enc_Whh: unused (encoder runs one step from h=0)
  p.ebih = (const float*)d_in[6];
  p.ebhh = (const float*)d_in[7];
  // d_in[8..10] attn_W/attn_b/v_W: unused (softmax over length-1 axis == 1)
  p.dW0  = (const float*)d_in[11];
  p.dW1  = (const float*)d_in[12];
  p.dW2  = (const float*)d_in[13];
  p.dWhh = (const float*)d_in[14];
  p.dbih = (const float*)d_in[15];
  p.dbhh = (const float*)d_in[16];
  p.outW = (const float*)d_in[17];
  p.outb = (const float*)d_in[18];
  p.out  = (float*)d_out;

  // Primary: cooperative single kernel. Checked; on refusal, multi-launch fallback.
  void* kargs[] = {&p};
  hipError_t e = hipLaunchCooperativeKernel((const void*)k_coop, dim3(NB), dim3(NT),
                                            kargs, 0, stream);
  if (e == hipSuccess) return;
  (void)hipGetLastError();  // clear sticky error

  hipLaunchKernelGGL(k_enc0, dim3(NB), dim3(NT), 0, stream, p);
  hipLaunchKernelGGL(k_encL, dim3(NB), dim3(NT), 0, stream, p, 1);
  hipLaunchKernelGGL(k_encL, dim3(NB), dim3(NT), 0, stream, p, 2);
  hipLaunchKernelGGL(k_base0, dim3(NB), dim3(NT), 0, stream, p);
  for (int t = 0; t < T; ++t) {
    hipLaunchKernelGGL(k_dec_s0, dim3(NB), dim3(NT), 0, stream, p, t);
    hipLaunchKernelGGL(k_dec_sL, dim3(NB), dim3(NT), 0, stream, p, t, 1);
    hipLaunchKernelGGL(k_dec_sL, dim3(NB), dim3(NT), 0, stream, p, t, 2);
  }
  hipLaunchKernelGGL(k_final, dim3(1), dim3(NT), 0, stream, p);
}

// Round 3
// 801.598 us; speedup vs baseline: 2.1046x; 2.1046x over previous
//
#include <hip/hip_runtime.h>
#include <cstddef>

constexpr int H  = 512;   // hidden
constexpr int F  = 21;    // features
constexpr int T  = 28;    // output steps
constexpr int NB = 128;   // blocks
constexpr int NT = 256;   // threads/block (4 waves) -> 512 waves total
constexpr int NW = NT / 64;

#define SCOPE_AGENT __HIP_MEMORY_SCOPE_AGENT

// Cross-block state. All accesses to these go through agent-scope atomics
// (write-through / cache-bypassing), so no acquire-invalidate is ever needed
// and the per-XCD L2 keeps the weights hot across all 88 phases.
__device__ float    g_enc[H];        // encoder output
__device__ float    g_h[2 * 3 * H];  // ping-pong h state [buf][layer][H]
__device__ unsigned g_bar;           // barrier arrival counter (self-resetting)

struct P {
  const float *x, *py, *eW0, *eW1, *eW2, *ebih, *ebhh;
  const float *dW0, *dW1, *dW2, *dWhh, *dbih, *dbhh, *outW, *outb;
  float* out;
};

__device__ __forceinline__ float sigm(float v)  { return 1.0f / (1.0f + __expf(-v)); }
__device__ __forceinline__ float tanh_f(float v){ return 1.0f - 2.0f / (__expf(2.0f * v) + 1.0f); }

__device__ __forceinline__ float cohload(const float* p) {
  return __hip_atomic_load(p, __ATOMIC_RELAXED, SCOPE_AGENT);
}
__device__ __forceinline__ void cohstore(float* p, float v) {
  __hip_atomic_store(p, v, __ATOMIC_RELAXED, SCOPE_AGENT);
}

__device__ __forceinline__ float4 wredsum4(float4 v) {
#pragma unroll
  for (int off = 32; off > 0; off >>= 1) {
    v.x += __shfl_xor(v.x, off, 64);
    v.y += __shfl_xor(v.y, off, 64);
    v.z += __shfl_xor(v.z, off, 64);
    v.w += __shfl_xor(v.w, off, 64);
  }
  return v;
}

__device__ __forceinline__ float wredsum1(float v) {
#pragma unroll
  for (int off = 32; off > 0; off >>= 1) v += __shfl_xor(v, off, 64);
  return v;
}

// Grid barrier WITHOUT hardware acquire: arrival is a release fetch_add
// (drains this block's coherent h-stores; L2 has no dirty shared lines so
// any writeback is cheap); the spin is a RELAXED agent load (sc-flagged,
// reads the coherence point, does NOT invalidate L2 -> weights stay hot).
// Data correctness comes from the data itself moving via agent-scope atomics.
__device__ __forceinline__ void gbar(unsigned& tgt) {
  __syncthreads();
  if (threadIdx.x == 0) {
    tgt += NB;
    __hip_atomic_fetch_add(&g_bar, 1u, __ATOMIC_RELEASE, SCOPE_AGENT);
    while (__hip_atomic_load(&g_bar, __ATOMIC_RELAXED, SCOPE_AGENT) < tgt) {}
    __atomic_signal_fence(__ATOMIC_SEQ_CST);  // no compiler reordering past the spin
  }
  __syncthreads();
}

// Stage one/two 512-float vectors from coherent global into LDS.
// 256 threads x consecutive dwords -> coalesced LLC reads.
__device__ __forceinline__ void stage1(const float* A, float* sA) {
  const int i = threadIdx.x;
  sA[i]      = cohload(A + i);
  sA[i + NT] = cohload(A + i + NT);
  __syncthreads();
}
__device__ __forceinline__ void stage2(const float* A, const float* B,
                                       float* sA, float* sB) {
  const int i = threadIdx.x;
  sA[i]      = cohload(A + i);
  sA[i + NT] = cohload(A + i + NT);
  sB[i]      = cohload(B + i);
  sB[i + NT] = cohload(B + i + NT);
  __syncthreads();
}

// 4 gate partial dots for row r; weights global (row-major ld=512), x in LDS.
__device__ __forceinline__ void dot4s(const float* __restrict__ W, int r, int lane,
                                      const float* sX, float* s) {
  float4 x0 = *(const float4*)(sX + lane * 8);
  float4 x1 = *(const float4*)(sX + lane * 8 + 4);
#pragma unroll
  for (int g = 0; g < 4; ++g) {
    const float* p = W + (size_t)(g * H + r) * H + lane * 8;
    float4 a = *(const float4*)(p);
    float4 b = *(const float4*)(p + 4);
    s[g] += a.x * x0.x + a.y * x0.y + a.z * x0.z + a.w * x0.w
          + b.x * x1.x + b.y * x1.y + b.z * x1.z + b.w * x1.w;
  }
}

// one row of y = out_W[j,:] . [h2 ; enc], both halves in LDS
__device__ __forceinline__ float ydot_lds(const float* __restrict__ outW,
                                          const float* sh2, const float* senc,
                                          int j, int lane) {
  const float4* wr = (const float4*)(outW + (size_t)j * (2 * H) + lane * 16);
  const float*  up = (lane < 32) ? (sh2 + lane * 16) : (senc + (lane - 32) * 16);
  float s = 0.f;
#pragma unroll
  for (int k = 0; k < 4; ++k) {
    float4 a = wr[k];
    float4 u = ((const float4*)up)[k];
    s += a.x * u.x + a.y * u.y + a.z * u.z + a.w * u.w;
  }
  return wredsum1(s);
}

__global__ __launch_bounds__(NT, 1)
void k_coop(P p) {
  const int lane = threadIdx.x & 63;
  const int w    = threadIdx.x >> 6;
  const int r    = blockIdx.x * NW + w;  // fixed wave->row mapping (L2 weight locality)

  __shared__ float sA[H], sB[H], senc[H], ly[32];
  unsigned tgt = 0;

  // Lane-0-held recurrent state: c per layer + precomputed base0 (4 gates).
  float c0 = 0.f, c1 = 0.f, c2 = 0.f;
  float b0[4] = {0.f, 0.f, 0.f, 0.f};

  // ---- Encoder layer 0: h=c=0 -> Whh term zero, f-gate dead ----
  {
    float s0 = 0.f, s1 = 0.f, s2 = 0.f, s3 = 0.f;
    if (lane < F) {
      const float xv = p.x[lane];
      s0 = p.eW0[(size_t)(0 * H + r) * F + lane] * xv;
      s1 = p.eW0[(size_t)(1 * H + r) * F + lane] * xv;
      s2 = p.eW0[(size_t)(2 * H + r) * F + lane] * xv;
      s3 = p.eW0[(size_t)(3 * H + r) * F + lane] * xv;
    }
    float4 v = wredsum4(make_float4(s0, s1, s2, s3));
    if (lane == 0) {
      const float* bi = p.ebih + r;
      const float* bh = p.ebhh + r;
      float cn = sigm(v.x + bi[0] + bh[0]) * tanh_f(v.z + bi[2 * H] + bh[2 * H]);
      c0 = cn;
      cohstore(&g_h[3 * H + r], sigm(v.w + bi[3 * H] + bh[3 * H]) * tanh_f(cn));
    }
  }
  gbar(tgt);

  // ---- Encoder layer 1 ----
  stage1(g_h + 3 * H, sA);
  {
    float s[4] = {0.f, 0.f, 0.f, 0.f};
    dot4s(p.eW1, r, lane, sA, s);
    float4 v = wredsum4(make_float4(s[0], s[1], s[2], s[3]));
    if (lane == 0) {
      const float* bi = p.ebih + 4 * H + r;
      const float* bh = p.ebhh + 4 * H + r;
      float cn = sigm(v.x + bi[0] + bh[0]) * tanh_f(v.z + bi[2 * H] + bh[2 * H]);
      c1 = cn;
      cohstore(&g_h[3 * H + H + r], sigm(v.w + bi[3 * H] + bh[3 * H]) * tanh_f(cn));
    }
  }
  gbar(tgt);

  // ---- Encoder layer 2 (-> enc_out) ----
  stage1(g_h + 3 * H + H, sA);
  {
    float s[4] = {0.f, 0.f, 0.f, 0.f};
    dot4s(p.eW2, r, lane, sA, s);
    float4 v = wredsum4(make_float4(s[0], s[1], s[2], s[3]));
    if (lane == 0) {
      const float* bi = p.ebih + 8 * H + r;
      const float* bh = p.ebhh + 8 * H + r;
      float cn = sigm(v.x + bi[0] + bh[0]) * tanh_f(v.z + bi[2 * H] + bh[2 * H]);
      c2 = cn;
      float hn = sigm(v.w + bi[3 * H] + bh[3 * H]) * tanh_f(cn);
      cohstore(&g_h[3 * H + 2 * H + r], hn);
      cohstore(&g_enc[r], hn);
    }
  }
  gbar(tgt);

  // ---- base0 = dec_Wih0[:, F:] @ enc + dbih0 + dbhh0 (lane-0 registers) ----
  stage1(g_enc, senc);  // senc persists for all steps (read-only afterwards)
  {
#pragma unroll
    for (int g = 0; g < 4; ++g) {
      const float* wrow = p.dW0 + (size_t)(g * H + r) * (H + F) + F;
      float s = 0.f;
      for (int j = lane; j < H; j += 64) s += wrow[j] * senc[j];
      s = wredsum1(s);
      if (lane == 0) b0[g] = s + p.dbih[g * H + r] + p.dbhh[g * H + r];
    }
  }
  gbar(tgt);

  // ---------------- Decoder: T steps x 3 phases ----------------
  for (int t = 0; t < T; ++t) {
    const int pb = t & 1, ob = pb ^ 1;
    float* hw = g_h + pb * 3 * H;
    float* hr = g_h + ob * 3 * H;

    // ---- S0: y(t-1) (block-redundant) + cell 0 ----
    stage2(hr, hr + 2 * H, sA, sB);  // sA = h0(t-1), sB = h2(t-1)
    if (t == 0) {
      if (threadIdx.x < F) ly[threadIdx.x] = p.py[threadIdx.x];
    } else {
      for (int j = w; j < F; j += NW) {
        float s = ydot_lds(p.outW, sB, senc, j, lane);
        if (lane == 0) ly[j] = s + p.outb[j];
      }
    }
    __syncthreads();
    if (t > 0 && blockIdx.x == 0 && threadIdx.x < F)
      p.out[(t - 1) * F + threadIdx.x] = ly[threadIdx.x];

    {
      float s[4] = {0.f, 0.f, 0.f, 0.f};
      dot4s(p.dWhh, r, lane, sA, s);  // Whh layer 0
      if (lane < F) {
        const float yv = ly[lane];
#pragma unroll
        for (int g = 0; g < 4; ++g)
          s[g] += p.dW0[(size_t)(g * H + r) * (H + F) + lane] * yv;
      }
      float4 v = wredsum4(make_float4(s[0], s[1], s[2], s[3]));
      if (lane == 0) {
        float cn = sigm(v.y + b0[1]) * c0 + sigm(v.x + b0[0]) * tanh_f(v.z + b0[2]);
        c0 = cn;
        cohstore(&hw[r], sigm(v.w + b0[3]) * tanh_f(cn));
      }
    }
    gbar(tgt);

    // ---- S1: cell 1 ----
    stage2(hw, hr + H, sA, sB);  // sA = h0(t), sB = h1(t-1)
    {
      float s[4] = {0.f, 0.f, 0.f, 0.f};
      dot4s(p.dW1, r, lane, sA, s);
      dot4s(p.dWhh + (size_t)4 * H * H, r, lane, sB, s);
      float4 v = wredsum4(make_float4(s[0], s[1], s[2], s[3]));
      if (lane == 0) {
        const float* bi = p.dbih + 4 * H + r;
        const float* bh = p.dbhh + 4 * H + r;
        float cn = sigm(v.y + bi[H] + bh[H]) * c1
                 + sigm(v.x + bi[0] + bh[0]) * tanh_f(v.z + bi[2 * H] + bh[2 * H]);
        c1 = cn;
        cohstore(&hw[H + r], sigm(v.w + bi[3 * H] + bh[3 * H]) * tanh_f(cn));
      }
    }
    gbar(tgt);

    // ---- S2: cell 2 ----
    stage2(hw + H, hr + 2 * H, sA, sB);  // sA = h1(t), sB = h2(t-1)
    {
      float s[4] = {0.f, 0.f, 0.f, 0.f};
      dot4s(p.dW2, r, lane, sA, s);
      dot4s(p.dWhh + (size_t)8 * H * H, r, lane, sB, s);
      float4 v = wredsum4(make_float4(s[0], s[1], s[2], s[3]));
      if (lane == 0) {
        const float* bi = p.dbih + 8 * H + r;
        const float* bh = p.dbhh + 8 * H + r;
        float cn = sigm(v.y + bi[H] + bh[H]) * c2
                 + sigm(v.x + bi[0] + bh[0]) * tanh_f(v.z + bi[2 * H] + bh[2 * H]);
        c2 = cn;
        cohstore(&hw[2 * H + r], sigm(v.w + bi[3 * H] + bh[3 * H]) * tanh_f(cn));
      }
    }
    gbar(tgt);
  }

  // ---- final y(T-1) (block 0 only; all barriers already passed) ----
  if (blockIdx.x == 0) {
    stage1(g_h + ((T - 1) & 1) * 3 * H + 2 * H, sB);
    for (int j = w; j < F; j += NW) {
      float s = ydot_lds(p.outW, sB, senc, j, lane);
      if (lane == 0) p.out[(T - 1) * F + j] = s + p.outb[j];
    }
  }

  // ---- self-reset of the barrier counter (last arriver writes 0) ----
  if (threadIdx.x == 0) {
    unsigned old = __hip_atomic_fetch_add(&g_bar, 1u, __ATOMIC_RELAXED, SCOPE_AGENT);
    if (old == tgt + NB - 1)
      __hip_atomic_store(&g_bar, 0u, __ATOMIC_RELAXED, SCOPE_AGENT);
  }
}

extern "C" void kernel_launch(void* const* d_in, const int* in_sizes, int n_in,
                              void* d_out, int out_size, void* d_ws, size_t ws_size,
                              hipStream_t stream) {
  P p;
  p.x    = (const float*)d_in[0];
  p.py   = (const float*)d_in[1];
  p.eW0  = (const float*)d_in[2];
  p.eW1  = (const float*)d_in[3];
  p.eW2  = (const float*)d_in[4];
  // d_in[5] enc_Whh: unused (encoder runs one step from h=0)
  p.ebih = (const float*)d_in[6];
  p.ebhh = (const float*)d_in[7];
  // d_in[8..10] attn_W/attn_b/v_W: unused (softmax over length-1 axis == 1)
  p.dW0  = (const float*)d_in[11];
  p.dW1  = (const float*)d_in[12];
  p.dW2  = (const float*)d_in[13];
  p.dWhh = (const float*)d_in[14];
  p.dbih = (const float*)d_in[15];
  p.dbhh = (const float*)d_in[16];
  p.outW = (const float*)d_in[17];
  p.outb = (const float*)d_in[18];
  p.out  = (float*)d_out;

  void* kargs[] = {&p};
  hipError_t e = hipLaunchCooperativeKernel((const void*)k_coop, dim3(NB), dim3(NT),
                                            kargs, 0, stream);
  if (e != hipSuccess) {
    (void)hipGetLastError();
    // 128 blocks of 256 threads trivially co-schedule on 256 CUs; plain launch
    // as a safety net (same kernel, custom barrier works once co-resident).
    hipLaunchKernelGGL(k_coop, dim3(NB), dim3(NT), 0, stream, p);
  }
}

// Round 4
// 539.547 us; speedup vs baseline: 3.1267x; 1.4857x over previous
//
#include <hip/hip_runtime.h>
#include <cstddef>

constexpr int H  = 512;   // hidden
constexpr int F  = 21;    // features
constexpr int T  = 28;    // output steps
constexpr int NB = 128;   // blocks (<= 256 CUs -> always co-resident, plain launch OK)
constexpr int NT = 256;   // threads/block (4 waves) -> 512 waves total
constexpr int NW = NT / 64;

#define SCOPE_AGENT __HIP_MEMORY_SCOPE_AGENT

// Tagged cross-block state: each element is (tag<<32)|float_bits, moved with
// relaxed agent-scope 8B atomics (sc1: bypass local caches, land in LLC).
// Consumers poll for the exact tag -> data-flow sync, NO grid barrier at all.
// Tag convention: value written at decoder step t' carries tag t'+2
// (encoder state is "t' = -1" -> tag 1). Slot parity: buf[t'&1].
__device__ unsigned long long g_hp[2][3][H];  // h state, ping-pong per layer
__device__ unsigned long long g_encp[H];      // encoder output (tag 1)
__device__ unsigned g_exit;                   // end-of-call exit counter

struct P {
  const float *x, *py, *eW0, *eW1, *eW2, *ebih, *ebhh;
  const float *dW0, *dW1, *dW2, *dWhh, *dbih, *dbhh, *outW, *outb;
  float* out;
};

__device__ __forceinline__ float sigm(float v)  { return 1.0f / (1.0f + __expf(-v)); }
__device__ __forceinline__ float tanh_f(float v){ return 1.0f - 2.0f / (__expf(2.0f * v) + 1.0f); }

__device__ __forceinline__ float4 wredsum4(float4 v) {
#pragma unroll
  for (int off = 32; off > 0; off >>= 1) {
    v.x += __shfl_xor(v.x, off, 64);
    v.y += __shfl_xor(v.y, off, 64);
    v.z += __shfl_xor(v.z, off, 64);
    v.w += __shfl_xor(v.w, off, 64);
  }
  return v;
}

__device__ __forceinline__ float wredsum1(float v) {
#pragma unroll
  for (int off = 32; off > 0; off >>= 1) v += __shfl_xor(v, off, 64);
  return v;
}

__device__ __forceinline__ void pstore(unsigned long long* slot, float v, unsigned tag) {
  union { float f; unsigned u; } c; c.f = v;
  unsigned long long pk = ((unsigned long long)tag << 32) | (unsigned long long)c.u;
  __hip_atomic_store(slot, pk, __ATOMIC_RELAXED, SCOPE_AGENT);
}

// Poll one element until its tag matches `want`. Cap the spin so a logic error
// degrades to a wrong answer (visible absmax fail), never a hang.
__device__ __forceinline__ float tagload(const unsigned long long* p, unsigned want) {
  unsigned long long v = __hip_atomic_load(p, __ATOMIC_RELAXED, SCOPE_AGENT);
  int guard = 0;
  while ((unsigned)(v >> 32) != want && ++guard < (1 << 20))
    v = __hip_atomic_load(p, __ATOMIC_RELAXED, SCOPE_AGENT);
  union { unsigned u; float f; } c; c.u = (unsigned)v;
  return c.f;
}

// Stage tagged vectors into LDS. Leading __syncthreads: WAR guard (previous
// phase's LDS readers must finish before we overwrite sA/sB).
__device__ __forceinline__ void stage1t(const unsigned long long* A, float* sA, unsigned wa) {
  __syncthreads();
  const int i = threadIdx.x;
  sA[i]      = tagload(A + i, wa);
  sA[i + NT] = tagload(A + i + NT, wa);
  __syncthreads();
}
__device__ __forceinline__ void stage2t(const unsigned long long* A, unsigned wa, float* sA,
                                        const unsigned long long* B, unsigned wb, float* sB) {
  __syncthreads();
  const int i = threadIdx.x;
  sA[i]      = tagload(A + i, wa);
  sA[i + NT] = tagload(A + i + NT, wa);
  sB[i]      = tagload(B + i, wb);
  sB[i + NT] = tagload(B + i + NT, wb);
  __syncthreads();
}

// 4 gate partial dots for row r; weights global (row-major, ld=512), x in LDS.
__device__ __forceinline__ void dot4s(const float* __restrict__ W, int r, int lane,
                                      const float* sX, float* s) {
  float4 x0 = *(const float4*)(sX + lane * 8);
  float4 x1 = *(const float4*)(sX + lane * 8 + 4);
#pragma unroll
  for (int g = 0; g < 4; ++g) {
    const float* p = W + (size_t)(g * H + r) * H + lane * 8;
    float4 a = *(const float4*)(p);
    float4 b = *(const float4*)(p + 4);
    s[g] += a.x * x0.x + a.y * x0.y + a.z * x0.z + a.w * x0.w
          + b.x * x1.x + b.y * x1.y + b.z * x1.z + b.w * x1.w;
  }
}

// one row of y = out_W[j,:] . [h2 ; enc], both halves in LDS
__device__ __forceinline__ float ydot_lds(const float* __restrict__ outW,
                                          const float* sh2, const float* senc,
                                          int j, int lane) {
  const float4* wr = (const float4*)(outW + (size_t)j * (2 * H) + lane * 16);
  const float*  up = (lane < 32) ? (sh2 + lane * 16) : (senc + (lane - 32) * 16);
  float s = 0.f;
#pragma unroll
  for (int k = 0; k < 4; ++k) {
    float4 a = wr[k];
    float4 u = ((const float4*)up)[k];
    s += a.x * u.x + a.y * u.y + a.z * u.z + a.w * u.w;
  }
  return wredsum1(s);
}

__global__ __launch_bounds__(NT, 1)
void k_flow(P p) {
  const int lane = threadIdx.x & 63;
  const int w    = threadIdx.x >> 6;
  const int r    = blockIdx.x * NW + w;  // fixed wave->row mapping (L2 weight locality)

  __shared__ float sA[H], sB[H], senc[H], ly[32];
  __shared__ int s_last;

  // Block-private recurrent state in lane-0 registers.
  float c0 = 0.f, c1 = 0.f, c2 = 0.f;
  float b0[4] = {0.f, 0.f, 0.f, 0.f};

  // ---- Encoder layer 0: h=c=0 -> Whh term zero, f-gate dead. tag 1 ----
  {
    float s0 = 0.f, s1 = 0.f, s2 = 0.f, s3 = 0.f;
    if (lane < F) {
      const float xv = p.x[lane];
      s0 = p.eW0[(size_t)(0 * H + r) * F + lane] * xv;
      s1 = p.eW0[(size_t)(1 * H + r) * F + lane] * xv;
      s2 = p.eW0[(size_t)(2 * H + r) * F + lane] * xv;
      s3 = p.eW0[(size_t)(3 * H + r) * F + lane] * xv;
    }
    float4 v = wredsum4(make_float4(s0, s1, s2, s3));
    if (lane == 0) {
      const float* bi = p.ebih + r;
      const float* bh = p.ebhh + r;
      float cn = sigm(v.x + bi[0] + bh[0]) * tanh_f(v.z + bi[2 * H] + bh[2 * H]);
      c0 = cn;
      pstore(&g_hp[1][0][r], sigm(v.w + bi[3 * H] + bh[3 * H]) * tanh_f(cn), 1u);
    }
  }

  // ---- Encoder layer 1 (consumes enc h0, tag 1) ----
  stage1t(g_hp[1][0], sA, 1u);
  {
    float s[4] = {0.f, 0.f, 0.f, 0.f};
    dot4s(p.eW1, r, lane, sA, s);
    float4 v = wredsum4(make_float4(s[0], s[1], s[2], s[3]));
    if (lane == 0) {
      const float* bi = p.ebih + 4 * H + r;
      const float* bh = p.ebhh + 4 * H + r;
      float cn = sigm(v.x + bi[0] + bh[0]) * tanh_f(v.z + bi[2 * H] + bh[2 * H]);
      c1 = cn;
      pstore(&g_hp[1][1][r], sigm(v.w + bi[3 * H] + bh[3 * H]) * tanh_f(cn), 1u);
    }
  }

  // ---- Encoder layer 2 -> enc_out (tag 1) ----
  stage1t(g_hp[1][1], sA, 1u);
  {
    float s[4] = {0.f, 0.f, 0.f, 0.f};
    dot4s(p.eW2, r, lane, sA, s);
    float4 v = wredsum4(make_float4(s[0], s[1], s[2], s[3]));
    if (lane == 0) {
      const float* bi = p.ebih + 8 * H + r;
      const float* bh = p.ebhh + 8 * H + r;
      float cn = sigm(v.x + bi[0] + bh[0]) * tanh_f(v.z + bi[2 * H] + bh[2 * H]);
      c2 = cn;
      float hn = sigm(v.w + bi[3 * H] + bh[3 * H]) * tanh_f(cn);
      pstore(&g_hp[1][2][r], hn, 1u);
      pstore(&g_encp[r], hn, 1u);
    }
  }

  // ---- senc (persistent) + base0 in lane-0 registers; no cross-block output ----
  stage1t(g_encp, senc, 1u);
  {
#pragma unroll
    for (int g = 0; g < 4; ++g) {
      const float* wrow = p.dW0 + (size_t)(g * H + r) * (H + F) + F;
      float s = 0.f;
      for (int j = lane; j < H; j += 64) s += wrow[j] * senc[j];
      s = wredsum1(s);
      if (lane == 0) b0[g] = s + p.dbih[g * H + r] + p.dbhh[g * H + r];
    }
  }

  // ---------------- Decoder: T steps x 3 phases, tag-synchronized ----------------
  for (int t = 0; t < T; ++t) {
    const int pb = t & 1, ob = pb ^ 1;
    const unsigned wn = (unsigned)(t + 2);  // tag for state written at step t
    const unsigned wo = (unsigned)(t + 1);  // tag for state written at step t-1 (enc: 1)

    // ---- S0: y(t-1) (block-redundant) + cell 0 ----
    stage2t(g_hp[ob][0], wo, sA, g_hp[ob][2], wo, sB);  // h0(t-1), h2(t-1)
    if (t == 0) {
      if (threadIdx.x < F) ly[threadIdx.x] = p.py[threadIdx.x];
    } else {
      for (int j = w; j < F; j += NW) {
        float s = ydot_lds(p.outW, sB, senc, j, lane);
        if (lane == 0) ly[j] = s + p.outb[j];
      }
    }
    __syncthreads();
    if (t > 0 && blockIdx.x == 0 && threadIdx.x < F)
      p.out[(t - 1) * F + threadIdx.x] = ly[threadIdx.x];

    {
      float s[4] = {0.f, 0.f, 0.f, 0.f};
      dot4s(p.dWhh, r, lane, sA, s);  // Whh layer 0 . h0(t-1)
      if (lane < F) {
        const float yv = ly[lane];
#pragma unroll
        for (int g = 0; g < 4; ++g)
          s[g] += p.dW0[(size_t)(g * H + r) * (H + F) + lane] * yv;
      }
      float4 v = wredsum4(make_float4(s[0], s[1], s[2], s[3]));
      if (lane == 0) {
        float cn = sigm(v.y + b0[1]) * c0 + sigm(v.x + b0[0]) * tanh_f(v.z + b0[2]);
        c0 = cn;
        pstore(&g_hp[pb][0][r], sigm(v.w + b0[3]) * tanh_f(cn), wn);
      }
    }

    // ---- S1: cell 1 ----
    stage2t(g_hp[pb][0], wn, sA, g_hp[ob][1], wo, sB);  // h0(t), h1(t-1)
    {
      float s[4] = {0.f, 0.f, 0.f, 0.f};
      dot4s(p.dW1, r, lane, sA, s);
      dot4s(p.dWhh + (size_t)4 * H * H, r, lane, sB, s);
      float4 v = wredsum4(make_float4(s[0], s[1], s[2], s[3]));
      if (lane == 0) {
        const float* bi = p.dbih + 4 * H + r;
        const float* bh = p.dbhh + 4 * H + r;
        float cn = sigm(v.y + bi[H] + bh[H]) * c1
                 + sigm(v.x + bi[0] + bh[0]) * tanh_f(v.z + bi[2 * H] + bh[2 * H]);
        c1 = cn;
        pstore(&g_hp[pb][1][r], sigm(v.w + bi[3 * H] + bh[3 * H]) * tanh_f(cn), wn);
      }
    }

    // ---- S2: cell 2 ----
    stage2t(g_hp[pb][1], wn, sA, g_hp[ob][2], wo, sB);  // h1(t), h2(t-1)
    {
      float s[4] = {0.f, 0.f, 0.f, 0.f};
      dot4s(p.dW2, r, lane, sA, s);
      dot4s(p.dWhh + (size_t)8 * H * H, r, lane, sB, s);
      float4 v = wredsum4(make_float4(s[0], s[1], s[2], s[3]));
      if (lane == 0) {
        const float* bi = p.dbih + 8 * H + r;
        const float* bh = p.dbhh + 8 * H + r;
        float cn = sigm(v.y + bi[H] + bh[H]) * c2
                 + sigm(v.x + bi[0] + bh[0]) * tanh_f(v.z + bi[2 * H] + bh[2 * H]);
        c2 = cn;
        pstore(&g_hp[pb][2][r], sigm(v.w + bi[3 * H] + bh[3 * H]) * tanh_f(cn), wn);
      }
    }
  }

  // ---- final y(T-1): block 0 only ----
  if (blockIdx.x == 0) {
    stage1t(g_hp[(T - 1) & 1][2], sB, (unsigned)(T + 1));
    for (int j = w; j < F; j += NW) {
      float s = ydot_lds(p.outW, sB, senc, j, lane);
      if (lane == 0) p.out[(T - 1) * F + j] = s + p.outb[j];
    }
  }

  // ---- Exit: last block to leave resets all tags (graph replays start clean).
  // A block exit-adds only after its last shared read, so the reset (which
  // requires all NB adds) cannot race any reader.
  __syncthreads();
  if (threadIdx.x == 0) {
    unsigned old = __hip_atomic_fetch_add(&g_exit, 1u, __ATOMIC_RELAXED, SCOPE_AGENT);
    s_last = (old == NB - 1) ? 1 : 0;
  }
  __syncthreads();
  if (s_last) {
    unsigned long long* z = &g_hp[0][0][0];
    for (int i = threadIdx.x; i < 2 * 3 * H; i += NT)
      __hip_atomic_store(z + i, 0ull, __ATOMIC_RELAXED, SCOPE_AGENT);
    for (int i = threadIdx.x; i < H; i += NT)
      __hip_atomic_store(&g_encp[i], 0ull, __ATOMIC_RELAXED, SCOPE_AGENT);
    if (threadIdx.x == 0)
      __hip_atomic_store(&g_exit, 0u, __ATOMIC_RELAXED, SCOPE_AGENT);
  }
}

extern "C" void kernel_launch(void* const* d_in, const int* in_sizes, int n_in,
                              void* d_out, int out_size, void* d_ws, size_t ws_size,
                              hipStream_t stream) {
  P p;
  p.x    = (const float*)d_in[0];
  p.py   = (const float*)d_in[1];
  p.eW0  = (const float*)d_in[2];
  p.eW1  = (const float*)d_in[3];
  p.eW2  = (const float*)d_in[4];
  // d_in[5] enc_Whh: unused (encoder runs one step from h=0)
  p.ebih = (const float*)d_in[6];
  p.ebhh = (const float*)d_in[7];
  // d_in[8..10] attn_W/attn_b/v_W: unused (softmax over length-1 axis == 1)
  p.dW0  = (const float*)d_in[11];
  p.dW1  = (const float*)d_in[12];
  p.dW2  = (const float*)d_in[13];
  p.dWhh = (const float*)d_in[14];
  p.dbih = (const float*)d_in[15];
  p.dbhh = (const float*)d_in[16];
  p.outW = (const float*)d_in[17];
  p.outb = (const float*)d_in[18];
  p.out  = (float*)d_out;

  // Plain launch: 128 blocks on 256 CUs are always co-resident; avoids
  // cooperative-launch overhead (R3: ~135us bench-vs-dispatch gap).
  hipLaunchKernelGGL(k_flow, dim3(NB), dim3(NT), 0, stream, p);
}